// Round 8
// baseline (159.390 us; speedup 1.0000x reference)
//
#include <hip/hip_runtime.h>
#include <math.h>

// AutoregressiveFlowLayer MI355X — round 17.
// R16 post-mortem (48us): occupancy stuck at 50% despite grid=3/CU and LDS/LB
// permitting 3 blocks. Revised model: VGPR allocation quantum {64,128,256}
// (learn_hip m69) -> 65..128-reg waves occupy 128-reg slots -> 4 waves/SIMD
// hard cap = 50% occupancy. R12/R13/R16 all measured exactly that. There is
// no 6-wave point: either <=64 regs (8 waves/SIMD) or 50%.
// R17 = register diet to <=64 TRUE demand (R15 forced 64 with ~80 demand and
// spilled; this reduces demand first):
//  - ao[4] -> wout_lds[64][136] LDS (17.4KB), P3 A-frags via ds_read_b128
//    (same bank-balanced pattern as h reads): -16 regs. a1+a2 stay (20 regs).
//  - xgh 1-deep; epilogue x re-loaded from global inputs (L2-hit, rows <=2
//    tiles old; f32 x = better accuracy): -LDS, -coupling.
//  - R15 2-barrier single-h-plane schedule (compact LDS; R15 passed — its
//    failure was spill, not the schedule).
// LDS = 8704*2 + 17408 + 2560 + 1024 = 38400B; x4 = 153.6KB <= 160 ✓.
// Grid 1024 = 4 blocks/CU exactly; __launch_bounds__(512,8).
// Failure signatures: WRITE_SIZE >> 10MB = spill (revert); occ ~62% = 3 blocks
// (shave LDS); occ 50% = quantum hypothesis wrong.

#define RR 32
#define DD 1024
#define HH 128
#define OO 64
#define TROWS 32
#define TILES_PER_BLOCK 8
#define BLOCKS_PER_R 32

#define SHP 136   // u16 stride, h planes [row][feat] (bank-balanced)
#define SXG 40    // u16 stride, xg plane [row][feat]
#define SSC 136   // u16 stride, weight staging / wout_lds [col][k]

typedef _Float16 f16x8_t __attribute__((ext_vector_type(8)));
typedef float f32x4_t __attribute__((ext_vector_type(4)));
typedef unsigned short u16;
typedef unsigned int u32;

__device__ __forceinline__ u16 f16b(float x) {
    _Float16 h = (_Float16)x;            // v_cvt_f16_f32, RNE
    union { _Float16 f; u16 u; } c; c.f = h; return c.u;
}
__device__ __forceinline__ f32x4_t mfma16h(f16x8_t a, f16x8_t b, f32x4_t c) {
    return __builtin_amdgcn_mfma_f32_16x16x32_f16(a, b, c, 0, 0, 0);
}

// stage [K x 32] weight slice (row-major [k][col], ld ldc, col offset c0) into
// fp16 [col][k] scratch (stride SSC), conflict-free 4x4 transpose. tid in [0,256).
__device__ __forceinline__ void stage_block16(const float* __restrict__ W,
                                              const int* __restrict__ M,
                                              int ldc, int c0, int K, u16* dst,
                                              int tid)
{
    const int kb = tid >> 3;
    const int cb = tid & 7;
    if (kb * 4 >= K) return;
    const int k0 = kb * 4;
    float e[4][4];
#pragma unroll
    for (int i = 0; i < 4; ++i) {
        const int o = ((k0 + i) * ldc + c0 + 4 * cb) >> 2;
        float4 w = ((const float4*)W)[o];
        int4   m = ((const int4*)M)[o];
        e[i][0] = m.x ? w.x : 0.f; e[i][1] = m.y ? w.y : 0.f;
        e[i][2] = m.z ? w.z : 0.f; e[i][3] = m.w ? w.w : 0.f;
    }
#pragma unroll
    for (int j = 0; j < 4; ++j) {
        ushort4 p;
        p.x = f16b(e[0][j]); p.y = f16b(e[1][j]);
        p.z = f16b(e[2][j]); p.w = f16b(e[3][j]);
        *(ushort4*)&dst[(4 * cb + j) * SSC + k0] = p;
    }
}

// ReLU + fp16 pack of 4 accumulator values, one 8B store.
__device__ __forceinline__ void relu_store16(u16* __restrict__ dst, int o, f32x4_t a)
{
    ushort4 s;
    s.x = f16b(fmaxf(a[0], 0.f));
    s.y = f16b(fmaxf(a[1], 0.f));
    s.z = f16b(fmaxf(a[2], 0.f));
    s.w = f16b(fmaxf(a[3], 0.f));
    *(ushort4*)&dst[o] = s;
}

__global__ __launch_bounds__(512, 8)
void made_flow_r17(const float* __restrict__ inputs,
                   const float* __restrict__ W1,
                   const float* __restrict__ W2,
                   const float* __restrict__ Wout,
                   const int* __restrict__ idx,
                   const int* __restrict__ valid,
                   const int* __restrict__ M1,
                   const int* __restrict__ M2,
                   const int* __restrict__ Mout,
                   float* __restrict__ out)
{
    __shared__ __align__(16) u16 h1s[TROWS * SHP];      // 8704 B (staging scratch A)
    __shared__ __align__(16) u16 h2s[TROWS * SHP];      // 8704 B (staging scratch B)
    __shared__ __align__(16) u16 wout_lds[OO * SSC];    // 17408 B (Wout^T resident)
    __shared__ __align__(16) u16 xgh[TROWS * SXG];      // 2560 B (1-deep)
    __shared__ __align__(16) float red2[2][TROWS][4];   // 1024 B
    // total 38400 B -> 4 blocks/CU

    u16* const scr  = h1s;
    u16* const scr2 = h2s;

    const int tid  = threadIdx.x;
    const int r    = blockIdx.x / BLOCKS_PER_R;
    const int rb   = blockIdx.x % BLOCKS_PER_R;
    const int lane = tid & 63;
    const int wave = tid >> 6;     // 0..7
    const int q    = lane >> 4;
    const int l16  = lane & 15;
    const int wm3  = wave & 3;     // P3: o-col group 16*wm3
    const int ni3  = wave >> 2;    // P3: batch-row half

    // per-lane metadata straight from global (no LDS arrays)
    const int grow = tid >> 4;     // 0..31 batch row (gather role)
    const int gg   = tid & 15;     // col pair (gather role)
    const int   ci0 = idx[r * RR + 2 * gg];
    const int   ci1 = idx[r * RR + 2 * gg + 1];
    const float cv0 = valid[r * RR + 2 * gg]     ? 1.f : 0.f;
    const float cv1 = valid[r * RR + 2 * gg + 1] ? 1.f : 0.f;
    const int j0  = 8 * wm3 + 2 * q;                    // epilogue cols
    const int   ij0 = idx[r * RR + j0];
    const int   ij1 = idx[r * RR + j0 + 1];
    const float vj0 = valid[r * RR + j0]     ? 1.f : 0.f;
    const float vj1 = valid[r * RR + j0 + 1] ? 1.f : 0.f;

    // ---- stage weights: a1,a2 -> regs; Wout^T -> resident LDS ----
    f16x8_t a1;        // W1^T: wave cols 16w+l16, k=q*8..
    f16x8_t a2[4];     // W2^T: [ks], wave cols 16w+l16
    {
        const float* W1r = W1 + r * RR * HH;   const int* M1r = M1 + r * RR * HH;
        const float* W2r = W2 + r * HH * HH;   const int* M2r = M2 + r * HH * HH;
        const float* Wor = Wout + r * HH * OO; const int* Mor = Mout + r * HH * OO;
        const int c = wave >> 1, h = wave & 1;
        for (int i = 0; i < 2; ++i) {
            __syncthreads();
            if (tid < 256) stage_block16(W2r, M2r, HH, 32 * (2 * i),     HH, scr,  tid);
            else           stage_block16(W2r, M2r, HH, 32 * (2 * i + 1), HH, scr2, tid - 256);
            __syncthreads();
            if (c == 2 * i) {
#pragma unroll
                for (int ks = 0; ks < 4; ++ks)
                    a2[ks] = *(const f16x8_t*)&scr[(16 * h + l16) * SSC + ks * 32 + q * 8];
            } else if (c == 2 * i + 1) {
#pragma unroll
                for (int ks = 0; ks < 4; ++ks)
                    a2[ks] = *(const f16x8_t*)&scr2[(16 * h + l16) * SSC + ks * 32 + q * 8];
            }
        }
        for (int i = 0; i < 2; ++i) {
            __syncthreads();
            if (tid < 256) stage_block16(W1r, M1r, HH, 32 * (2 * i),     RR, scr,  tid);
            else           stage_block16(W1r, M1r, HH, 32 * (2 * i + 1), RR, scr2, tid - 256);
            __syncthreads();
            if (c == 2 * i)          a1 = *(const f16x8_t*)&scr [(16 * h + l16) * SSC + q * 8];
            else if (c == 2 * i + 1) a1 = *(const f16x8_t*)&scr2[(16 * h + l16) * SSC + q * 8];
        }
        // Wout^T -> wout_lds (stays for the whole kernel)
        __syncthreads();
        if (tid < 256) stage_block16(Wor, Mor, OO, 0,  HH, wout_lds,            tid);
        else           stage_block16(Wor, Mor, OO, 32, HH, wout_lds + 32 * SSC, tid - 256);
    }
    __syncthreads();   // staging done before xg/h1 writes

    const f32x4_t zero4 = {0.f, 0.f, 0.f, 0.f};
    const int gbase = (rb * TILES_PER_BLOCK * TROWS + grow) * DD;
    const int erow  = (rb * TILES_PER_BLOCK * TROWS + 16 * ni3 + l16) * DD;  // epilogue row base

    // ---- prologue: gather(0) -> xgh; issue gather(1) into regs ----
    float gx0, gx1;
    {
        float a0  = inputs[gbase + ci0] * cv0;
        float a1v = inputs[gbase + ci1] * cv1;
        *(u32*)&xgh[grow * SXG + 2 * gg] = (u32)f16b(a0) | ((u32)f16b(a1v) << 16);
        gx0 = inputs[gbase + TROWS * DD + ci0] * cv0;
        gx1 = inputs[gbase + TROWS * DD + ci1] * cv1;
    }
    __syncthreads();

    // ---- prologue: P1(0) -> h1s ----
    {
#pragma unroll
        for (int ni = 0; ni < 2; ++ni) {
            f16x8_t b = *(const f16x8_t*)&xgh[(16 * ni + l16) * SXG + q * 8];
            f32x4_t a = mfma16h(a1, b, zero4);
            relu_store16(h1s, (16 * ni + l16) * SHP + 16 * wave + 4 * q, a);
        }
    }

    for (int t = 0; t < TILES_PER_BLOCK; ++t) {
        __syncthreads();   // head barrier

        const bool dg = (t + 1 < TILES_PER_BLOCK);

        // ========== interval A: gather-store(t+1) + P2(t) + out-store(t-2) ========
        if (dg) {
            *(u32*)&xgh[grow * SXG + 2 * gg] =
                (u32)f16b(gx0) | ((u32)f16b(gx1) << 16);
        }
        {
            // P2(t): h2^T = W2^T @ h1^T (wave owns 16 of M=128 cols, both ni, K=128)
            f32x4_t acc[2] = {zero4, zero4};
#pragma unroll
            for (int ks = 0; ks < 4; ++ks) {
#pragma unroll
                for (int ni = 0; ni < 2; ++ni) {
                    f16x8_t b = *(const f16x8_t*)&h1s[(16 * ni + l16) * SHP + ks * 32 + q * 8];
                    acc[ni] = mfma16h(a2[ks], b, acc[ni]);
                }
            }
#pragma unroll
            for (int ni = 0; ni < 2; ++ni)
                relu_store16(h2s, (16 * ni + l16) * SHP + 16 * wave + 4 * q, acc[ni]);
        }
        if (t >= 2 && tid < TROWS) {
            float4 rv = *(const float4*)&red2[t & 1][tid][0];
            out[((rb * TILES_PER_BLOCK + (t - 2)) * TROWS + tid) * RR + r] =
                rv.x + rv.y + rv.z + rv.w;
        }
        __syncthreads();   // mid barrier

        // ========== interval B: issues + P3(t) + P1(t+1) + epilogue(t) ============
        // long-latency issues first: gather(t+2) and epilogue x(t) from global
        if (t + 2 < TILES_PER_BLOCK) {
            const int base = gbase + (t + 2) * (TROWS * DD);
            gx0 = inputs[base + ci0] * cv0;
            gx1 = inputs[base + ci1] * cv1;
        }
        const float xv0 = inputs[erow + t * (TROWS * DD) + ij0];
        const float xv1 = inputs[erow + t * (TROWS * DD) + ij1];

        // P3(t): out^T = Wout^T @ h2^T; wave (wm3,ni3): o=16*wm3+4q+i, row=16*ni3+l16
        f32x4_t acc3 = zero4;
#pragma unroll
        for (int ks = 0; ks < 4; ++ks) {
            f16x8_t ao = *(const f16x8_t*)&wout_lds[(16 * wm3 + l16) * SSC + ks * 32 + q * 8];
            f16x8_t b  = *(const f16x8_t*)&h2s[(16 * ni3 + l16) * SHP + ks * 32 + q * 8];
            acc3 = mfma16h(ao, b, acc3);
        }

        if (dg) {   // P1(t+1): h1^T = W1^T @ xg^T
#pragma unroll
            for (int ni = 0; ni < 2; ++ni) {
                f16x8_t b = *(const f16x8_t*)&xgh[(16 * ni + l16) * SXG + q * 8];
                f32x4_t a = mfma16h(a1, b, zero4);
                relu_store16(h1s, (16 * ni + l16) * SHP + 16 * wave + 4 * q, a);
            }
        }

        {   // epilogue(t): acc3[i]: i even=shift(j), i odd=log_s(j), j=8*wm3+2q+(i>>1)
            const int row = 16 * ni3 + l16;
            const float u0 = (xv0 * vj0 - acc3[0]) * __expf(-acc3[1]);
            const float u1 = (xv1 * vj1 - acc3[2]) * __expf(-acc3[3]);
            float p = (-0.5f * u0 * u0 - 0.91893853320467266954f - acc3[1]) * vj0
                    + (-0.5f * u1 * u1 - 0.91893853320467266954f - acc3[3]) * vj1;
            p += __shfl_xor(p, 16, 64);
            p += __shfl_xor(p, 32, 64);
            if (q == 0) red2[t & 1][row][wm3] = p;
        }
    }

    // ---- tail: store tiles T-2 and T-1 ----
    __syncthreads();
    if (tid < 2 * TROWS) {
        const int tt  = TILES_PER_BLOCK - 2 + (tid >> 5);   // T-2, T-1
        const int row = tid & 31;
        float4 rv = *(const float4*)&red2[tt & 1][row][0];
        out[((rb * TILES_PER_BLOCK + tt) * TROWS + row) * RR + r] =
            rv.x + rv.y + rv.z + rv.w;
    }
}

extern "C" void kernel_launch(void* const* d_in, const int* in_sizes, int n_in,
                              void* d_out, int out_size, void* d_ws, size_t ws_size,
                              hipStream_t stream)
{
    const float* inputs = (const float*)d_in[0];
    const float* W1     = (const float*)d_in[1];
    const float* W2     = (const float*)d_in[2];
    const float* Wout   = (const float*)d_in[3];
    const int*   idx    = (const int*)d_in[4];
    const int*   valid  = (const int*)d_in[5];
    const int*   M1     = (const int*)d_in[6];
    const int*   M2     = (const int*)d_in[7];
    const int*   Mout   = (const int*)d_in[8];
    float*       out    = (float*)d_out;

    hipLaunchKernelGGL(made_flow_r17, dim3(RR * BLOCKS_PER_R), dim3(512), 0, stream,
                       inputs, W1, W2, Wout, idx, valid, M1, M2, Mout, out);
}

// Round 9
// 141.570 us; speedup vs baseline: 1.1259x; 1.1259x over previous
//
#include <hip/hip_runtime.h>
#include <math.h>

// AutoregressiveFlowLayer MI355X — round 18.
// R17 post-mortem (spill AGAIN at (512,8): WRITE 38.5MB, 85us): <=64-reg point
// does not exist for this kernel (demand ~78). ~50% occupancy is the ceiling;
// occupancy axis CLOSED. Best verified: R16 48us, (512,6), no spill, all pipes
// <=26%.
// R18 = WAVE SPECIALIZATION at R16's operating point. In R16 all 8 waves run
// P1+P2+P3 -> each reads the ENTIRE h1/h2 panels (8-way duplicated LDS reads,
// 112 b128/tile) and issues a 14-MFMA+14-read serial stream per interval.
// Specialize: waves 0-3 = P2(t) (own 32/128 cols, 16 MFMA, 8 reads);
// waves 4-5 = P3(t-1)+epilogue (own 32/64 o-cols, 16 MFMA, 8 reads);
// waves 6-7 = P1(t+1) (own 64/128 cols, 8 MFMA, 2 reads); gather on all waves.
// One wf[8] frag array per wave holds that wave's weight panel -> register
// demand ~78 (<=85, no spill at (512,6)). LDS reads 112 -> 52 b128/tile (-54%).
// Same grid 768 (11/10 tiles), same single-barrier loop, same LDS 51.3KB.
// Predict: 48 -> 38-42us; conflicts 6.3M -> ~3M; WRITE ~1MB (spill check).

#define RR 32
#define DD 1024
#define HH 128
#define OO 64
#define TROWS 32
#define BLOCKS_PER_R 24
#define MAXT 11

#define SHP 136   // u16 stride, h planes [row][feat] (bank-balanced)
#define SXG 40    // u16 stride, xg plane [row][feat]
#define SSC 136   // u16 stride, weight staging [col][k]

typedef _Float16 f16x8_t __attribute__((ext_vector_type(8)));
typedef float f32x4_t __attribute__((ext_vector_type(4)));
typedef unsigned short u16;
typedef unsigned int u32;

__device__ __forceinline__ u16 f16b(float x) {
    _Float16 h = (_Float16)x;            // v_cvt_f16_f32, RNE
    union { _Float16 f; u16 u; } c; c.f = h; return c.u;
}
__device__ __forceinline__ f32x4_t mfma16h(f16x8_t a, f16x8_t b, f32x4_t c) {
    return __builtin_amdgcn_mfma_f32_16x16x32_f16(a, b, c, 0, 0, 0);
}

// stage [K x 32] weight slice (row-major [k][col], ld ldc, col offset c0) into
// fp16 [col][k] scratch (stride SSC), conflict-free 4x4 transpose. tid in [0,256).
__device__ __forceinline__ void stage_block16(const float* __restrict__ W,
                                              const int* __restrict__ M,
                                              int ldc, int c0, int K, u16* dst,
                                              int tid)
{
    const int kb = tid >> 3;
    const int cb = tid & 7;
    if (kb * 4 >= K) return;
    const int k0 = kb * 4;
    float e[4][4];
#pragma unroll
    for (int i = 0; i < 4; ++i) {
        const int o = ((k0 + i) * ldc + c0 + 4 * cb) >> 2;
        float4 w = ((const float4*)W)[o];
        int4   m = ((const int4*)M)[o];
        e[i][0] = m.x ? w.x : 0.f; e[i][1] = m.y ? w.y : 0.f;
        e[i][2] = m.z ? w.z : 0.f; e[i][3] = m.w ? w.w : 0.f;
    }
#pragma unroll
    for (int j = 0; j < 4; ++j) {
        ushort4 p;
        p.x = f16b(e[0][j]); p.y = f16b(e[1][j]);
        p.z = f16b(e[2][j]); p.w = f16b(e[3][j]);
        *(ushort4*)&dst[(4 * cb + j) * SSC + k0] = p;
    }
}

// ReLU + fp16 pack of 4 accumulator values, one 8B store.
__device__ __forceinline__ void relu_store16(u16* __restrict__ dst, int o, f32x4_t a)
{
    ushort4 s;
    s.x = f16b(fmaxf(a[0], 0.f));
    s.y = f16b(fmaxf(a[1], 0.f));
    s.z = f16b(fmaxf(a[2], 0.f));
    s.w = f16b(fmaxf(a[3], 0.f));
    *(ushort4*)&dst[o] = s;
}

__global__ __launch_bounds__(512, 6)
void made_flow_r18(const float* __restrict__ inputs,
                   const float* __restrict__ W1,
                   const float* __restrict__ W2,
                   const float* __restrict__ Wout,
                   const int* __restrict__ idx,
                   const int* __restrict__ valid,
                   const int* __restrict__ M1,
                   const int* __restrict__ M2,
                   const int* __restrict__ Mout,
                   float* __restrict__ out)
{
    __shared__ __align__(16) u16 h1s[2][TROWS * SHP];   // 17408 B (also staging scratch)
    __shared__ __align__(16) u16 h2s[2][TROWS * SHP];   // 17408 B
    __shared__ __align__(16) u16 xgh[4][TROWS * SXG];   // 10240 B
    __shared__ __align__(16) float red_all[MAXT][TROWS][4];  // 5632 B
    __shared__ int   idx_s[RR];
    __shared__ float v_s[RR];
    // total ~51.3 KB

    u16* const scr  = h1s[0];
    u16* const scr2 = h1s[1];

    const int tid  = threadIdx.x;
    const int r    = blockIdx.x / BLOCKS_PER_R;
    const int rb   = blockIdx.x % BLOCKS_PER_R;
    // tile range: first 16 blocks take 11 tiles, last 8 take 10 (total 256)
    const int ts   = (rb < 16) ? 11 * rb : 176 + 10 * (rb - 16);
    const int nt   = (rb < 16) ? 11 : 10;

    const int lane = tid & 63;
    const int wave = tid >> 6;     // 0..7
    const int q    = lane >> 4;
    const int l16  = lane & 15;
    const int w2   = wave - 4;     // P3 role: o-col group (0,1)
    const int w1r  = wave - 6;     // P1 role: col group (0,1)

    if (tid < RR) {
        idx_s[tid] = idx[r * RR + tid];
        v_s[tid]   = valid[r * RR + tid] ? 1.f : 0.f;
    }

    // ---- stage weights: per-role wf[8] register frags (W^T panels) ----
    f16x8_t wf[8];
    {
        const float* W1r = W1 + r * RR * HH;   const int* M1r = M1 + r * RR * HH;
        const float* W2r = W2 + r * HH * HH;   const int* M2r = M2 + r * HH * HH;
        const float* Wor = Wout + r * HH * OO; const int* Mor = Mout + r * HH * OO;
        // W2: 4 chunks of 32 cols, 2 rounds. wave w (0..3) takes chunk w.
        for (int i = 0; i < 2; ++i) {
            __syncthreads();
            if (tid < 256) stage_block16(W2r, M2r, HH, 32 * (2 * i),     HH, scr,  tid);
            else           stage_block16(W2r, M2r, HH, 32 * (2 * i + 1), HH, scr2, tid - 256);
            __syncthreads();
            if (wave == 2 * i) {
#pragma unroll
                for (int ks = 0; ks < 4; ++ks)
#pragma unroll
                    for (int mi = 0; mi < 2; ++mi)
                        wf[2 * ks + mi] = *(const f16x8_t*)&scr[(16 * mi + l16) * SSC + ks * 32 + q * 8];
            } else if (wave == 2 * i + 1) {
#pragma unroll
                for (int ks = 0; ks < 4; ++ks)
#pragma unroll
                    for (int mi = 0; mi < 2; ++mi)
                        wf[2 * ks + mi] = *(const f16x8_t*)&scr2[(16 * mi + l16) * SSC + ks * 32 + q * 8];
            }
        }
        // Wout: 2 chunks, 1 round. wave 4 -> chunk 0, wave 5 -> chunk 1.
        {
            __syncthreads();
            if (tid < 256) stage_block16(Wor, Mor, OO, 0,  HH, scr,  tid);
            else           stage_block16(Wor, Mor, OO, 32, HH, scr2, tid - 256);
            __syncthreads();
            if (wave == 4) {
#pragma unroll
                for (int ks = 0; ks < 4; ++ks)
#pragma unroll
                    for (int mi = 0; mi < 2; ++mi)
                        wf[2 * ks + mi] = *(const f16x8_t*)&scr[(16 * mi + l16) * SSC + ks * 32 + q * 8];
            } else if (wave == 5) {
#pragma unroll
                for (int ks = 0; ks < 4; ++ks)
#pragma unroll
                    for (int mi = 0; mi < 2; ++mi)
                        wf[2 * ks + mi] = *(const f16x8_t*)&scr2[(16 * mi + l16) * SSC + ks * 32 + q * 8];
            }
        }
        // W1 (K=32): 4 chunks, 2 rounds. wave 6 -> chunks 0,1; wave 7 -> 2,3.
        for (int i = 0; i < 2; ++i) {
            __syncthreads();
            if (tid < 256) stage_block16(W1r, M1r, HH, 32 * (2 * i),     RR, scr,  tid);
            else           stage_block16(W1r, M1r, HH, 32 * (2 * i + 1), RR, scr2, tid - 256);
            __syncthreads();
            if (wave == 6 + i) {
#pragma unroll
                for (int mi = 0; mi < 2; ++mi) {
                    wf[mi]     = *(const f16x8_t*)&scr [(16 * mi + l16) * SSC + q * 8];
                    wf[2 + mi] = *(const f16x8_t*)&scr2[(16 * mi + l16) * SSC + q * 8];
                }
            }
        }
    }
    __syncthreads();   // staging done; v_s/idx_s also visible

    // P3-role epilogue constants (uniform-allocated, used by waves 4-5)
    const int ew2 = (w2 < 0 || w2 > 1) ? 0 : w2;
    float vjm[2][2];
#pragma unroll
    for (int mi = 0; mi < 2; ++mi) {
        vjm[mi][0] = v_s[16 * ew2 + 8 * mi + 2 * q];
        vjm[mi][1] = v_s[16 * ew2 + 8 * mi + 2 * q + 1];
    }

    const f32x4_t zero4 = {0.f, 0.f, 0.f, 0.f};
    const int grow = tid >> 4;     // 0..31 batch row (gather role, all waves)
    const int gg   = tid & 15;     // col pair
    const int   ci0 = idx_s[2 * gg], ci1 = idx_s[2 * gg + 1];
    const float cv0 = v_s[2 * gg],   cv1 = v_s[2 * gg + 1];
    const int   gbase = (ts * TROWS + grow) * DD;

    // ---- prologue: gather(0),(1) ----
    {
        float a0  = inputs[gbase + ci0] * cv0;
        float a1v = inputs[gbase + ci1] * cv1;
        float b0  = inputs[gbase + TROWS * DD + ci0] * cv0;
        float b1  = inputs[gbase + TROWS * DD + ci1] * cv1;
        *(u32*)&xgh[0][grow * SXG + 2 * gg] = (u32)f16b(a0) | ((u32)f16b(a1v) << 16);
        *(u32*)&xgh[1][grow * SXG + 2 * gg] = (u32)f16b(b0) | ((u32)f16b(b1) << 16);
    }
    __syncthreads();

    // ---- prologue: P1(0) -> h1s[0] (waves 6,7 only) ----
    if (wave >= 6) {
#pragma unroll
        for (int ni = 0; ni < 2; ++ni) {
            f16x8_t b = *(const f16x8_t*)&xgh[0][(16 * ni + l16) * SXG + q * 8];
#pragma unroll
            for (int mi = 0; mi < 4; ++mi) {
                f32x4_t a = mfma16h(wf[mi], b, zero4);
                relu_store16(h1s[0], (16 * ni + l16) * SHP + 64 * w1r + 16 * mi + 4 * q, a);
            }
        }
    }

    // ---- main loop: ONE barrier per tile; waves specialized by role ----
    for (int t = 0; t <= nt; ++t) {
        __syncthreads();

        const bool doG = (t + 2 < nt);
        float gx0, gx1;
        if (doG) {   // gather-issue(t+2), all waves, longest latency first
            const int base = gbase + (t + 2) * (TROWS * DD);
            gx0 = inputs[base + ci0] * cv0;
            gx1 = inputs[base + ci1] * cv1;
        }

        if (wave < 4) {
            // P2(t): wave owns cols [32*wave, 32*wave+32); 16 MFMA, 8 B-reads
            if (t < nt) {
                const u16* h1b = h1s[t & 1];
                u16*       h2b = h2s[t & 1];
                f32x4_t acc[2][2] = {{zero4, zero4}, {zero4, zero4}};
#pragma unroll
                for (int ks = 0; ks < 4; ++ks) {
#pragma unroll
                    for (int ni = 0; ni < 2; ++ni) {
                        f16x8_t b = *(const f16x8_t*)&h1b[(16 * ni + l16) * SHP + ks * 32 + q * 8];
#pragma unroll
                        for (int mi = 0; mi < 2; ++mi)
                            acc[mi][ni] = mfma16h(wf[2 * ks + mi], b, acc[mi][ni]);
                    }
                }
#pragma unroll
                for (int mi = 0; mi < 2; ++mi)
#pragma unroll
                    for (int ni = 0; ni < 2; ++ni)
                        relu_store16(h2b, (16 * ni + l16) * SHP + 32 * wave + 16 * mi + 4 * q,
                                     acc[mi][ni]);
            }
        } else if (wave < 6) {
            // P3(t-1)+epilogue: wave owns o-cols [32*w2, 32*w2+32); 16 MFMA, 8 reads
            if (t >= 1) {
                const u16* h2b = h2s[(t - 1) & 1];
                f32x4_t a3[2][2] = {{zero4, zero4}, {zero4, zero4}};
#pragma unroll
                for (int ks = 0; ks < 4; ++ks) {
#pragma unroll
                    for (int ni = 0; ni < 2; ++ni) {
                        f16x8_t b = *(const f16x8_t*)&h2b[(16 * ni + l16) * SHP + ks * 32 + q * 8];
#pragma unroll
                        for (int mi = 0; mi < 2; ++mi)
                            a3[mi][ni] = mfma16h(wf[2 * ks + mi], b, a3[mi][ni]);
                    }
                }
                // epilogue: acc i even=shift(j), i odd=log_s(j); j0 = 16*w2+8*mi+2*q
#pragma unroll
                for (int mi = 0; mi < 2; ++mi) {
                    const int j0 = 16 * ew2 + 8 * mi + 2 * q;
#pragma unroll
                    for (int ni = 0; ni < 2; ++ni) {
                        const int row = 16 * ni + l16;
                        u32 xw = *(const u32*)&xgh[(t - 1) & 3][row * SXG + j0];
                        union { u32 u; _Float16 h[2]; } xc; xc.u = xw;
                        const float xv0 = (float)xc.h[0], xv1 = (float)xc.h[1];
                        f32x4_t a = a3[mi][ni];
                        const float u0 = (xv0 - a[0]) * __expf(-a[1]);
                        const float u1 = (xv1 - a[2]) * __expf(-a[3]);
                        float p = (-0.5f * u0 * u0 - 0.91893853320467266954f - a[1]) * vjm[mi][0]
                                + (-0.5f * u1 * u1 - 0.91893853320467266954f - a[3]) * vjm[mi][1];
                        p += __shfl_xor(p, 16, 64);
                        p += __shfl_xor(p, 32, 64);
                        if (q == 0) red_all[t - 1][row][2 * ew2 + mi] = p;
                    }
                }
            }
        } else {
            // P1(t+1): wave owns cols [64*w1r, 64*w1r+64); 8 MFMA, 2 B-reads
            if (t + 1 < nt) {
                const u16* xb  = xgh[(t + 1) & 3];
                u16*       h1b = h1s[(t + 1) & 1];
#pragma unroll
                for (int ni = 0; ni < 2; ++ni) {
                    f16x8_t b = *(const f16x8_t*)&xb[(16 * ni + l16) * SXG + q * 8];
#pragma unroll
                    for (int mi = 0; mi < 4; ++mi) {
                        f32x4_t a = mfma16h(wf[mi], b, zero4);
                        relu_store16(h1b, (16 * ni + l16) * SHP + 64 * w1r + 16 * mi + 4 * q, a);
                    }
                }
            }
        }

        if (doG) {   // gather-store(t+2), all waves
            *(u32*)&xgh[(t + 2) & 3][grow * SXG + 2 * gg] =
                (u32)f16b(gx0) | ((u32)f16b(gx1) << 16);
        }
    }

    // ---- tail: reduce red_all, single batched global store ----
    __syncthreads();
    if (tid < nt * TROWS) {
        const int tt  = tid >> 5;      // 0..nt-1
        const int row = tid & 31;
        float4 rv = *(const float4*)&red_all[tt][row][0];
        out[((ts + tt) * TROWS + row) * RR + r] =
            rv.x + rv.y + rv.z + rv.w;
    }
}

extern "C" void kernel_launch(void* const* d_in, const int* in_sizes, int n_in,
                              void* d_out, int out_size, void* d_ws, size_t ws_size,
                              hipStream_t stream)
{
    const float* inputs = (const float*)d_in[0];
    const float* W1     = (const float*)d_in[1];
    const float* W2     = (const float*)d_in[2];
    const float* Wout   = (const float*)d_in[3];
    const int*   idx    = (const int*)d_in[4];
    const int*   valid  = (const int*)d_in[5];
    const int*   M1     = (const int*)d_in[6];
    const int*   M2     = (const int*)d_in[7];
    const int*   Mout   = (const int*)d_in[8];
    float*       out    = (float*)d_out;

    hipLaunchKernelGGL(made_flow_r18, dim3(RR * BLOCKS_PER_R), dim3(512), 0, stream,
                       inputs, W1, W2, Wout, idx, valid, M1, M2, Mout, out);
}

// Round 10
// 119.965 us; speedup vs baseline: 1.3286x; 1.1801x over previous
//
#include <hip/hip_runtime.h>
#include <math.h>

// AutoregressiveFlowLayer MI355X — round 19.
// R18 post-mortem (REGRESSION 66us, WRITE 19.5MB spill): specialization's
// role-union + wf[8] blew past 85 regs AND imbalanced roles made every barrier
// wait on the slowest wave. Conflicts halved as predicted (6.3->4.3M) — the
// duplication model was right but LDS throughput isn't the gate. Reverted.
// Key re-read of R16: at (512,6), 3 blocks/CU requires <=85 combined regs/wave
// (512-reg file / 6 waves); measured 50% occupancy => R16 demand in (85,102].
// Target is <=85, NOT <=64 (R17's fatal over-reach). R17's diet (-16: Wout to
// LDS) is exactly the right size — it failed only via the (512,8) cap.
// R19 = three individually-validated pieces:
//  (1) R15's 2-barrier single-h-plane schedule (passed; failed only by spill),
//  (2) R17's diet: Wout^T resident in wout_lds, P3 A-frags via 4 bank-balanced
//      ds_read_b128/tile (a1+a2 stay in regs: 20),
//  (3) R16's grid=768 residency matching (BLOCKS_PER_R 24, 11/10 tiles).
// Demand ~79 <= 85 -> no spill, 6 waves/SIMD, 3 blocks/CU.
// LDS = 8704(h1)+8704(h2)+17408(wout)+5120(xgh2)+1024(red2)+384 = 41.3KB;
// x3 = 124KB <= 160 ✓.
// Checks: WRITE ~1MB + VGPR<=~72 = no spill; occupancy 70-75 = 3 blocks.

#define RR 32
#define DD 1024
#define HH 128
#define OO 64
#define TROWS 32
#define BLOCKS_PER_R 24

#define SHP 136   // u16 stride, h planes [row][feat] (bank-balanced)
#define SXG 40    // u16 stride, xg plane [row][feat]
#define SSC 136   // u16 stride, weight staging / wout_lds [col][k]

typedef _Float16 f16x8_t __attribute__((ext_vector_type(8)));
typedef float f32x4_t __attribute__((ext_vector_type(4)));
typedef unsigned short u16;
typedef unsigned int u32;

__device__ __forceinline__ u16 f16b(float x) {
    _Float16 h = (_Float16)x;            // v_cvt_f16_f32, RNE
    union { _Float16 f; u16 u; } c; c.f = h; return c.u;
}
__device__ __forceinline__ f32x4_t mfma16h(f16x8_t a, f16x8_t b, f32x4_t c) {
    return __builtin_amdgcn_mfma_f32_16x16x32_f16(a, b, c, 0, 0, 0);
}

// stage [K x 32] weight slice (row-major [k][col], ld ldc, col offset c0) into
// fp16 [col][k] scratch (stride SSC), conflict-free 4x4 transpose. tid in [0,256).
__device__ __forceinline__ void stage_block16(const float* __restrict__ W,
                                              const int* __restrict__ M,
                                              int ldc, int c0, int K, u16* dst,
                                              int tid)
{
    const int kb = tid >> 3;
    const int cb = tid & 7;
    if (kb * 4 >= K) return;
    const int k0 = kb * 4;
    float e[4][4];
#pragma unroll
    for (int i = 0; i < 4; ++i) {
        const int o = ((k0 + i) * ldc + c0 + 4 * cb) >> 2;
        float4 w = ((const float4*)W)[o];
        int4   m = ((const int4*)M)[o];
        e[i][0] = m.x ? w.x : 0.f; e[i][1] = m.y ? w.y : 0.f;
        e[i][2] = m.z ? w.z : 0.f; e[i][3] = m.w ? w.w : 0.f;
    }
#pragma unroll
    for (int j = 0; j < 4; ++j) {
        ushort4 p;
        p.x = f16b(e[0][j]); p.y = f16b(e[1][j]);
        p.z = f16b(e[2][j]); p.w = f16b(e[3][j]);
        *(ushort4*)&dst[(4 * cb + j) * SSC + k0] = p;
    }
}

// ReLU + fp16 pack of 4 accumulator values, one 8B store.
__device__ __forceinline__ void relu_store16(u16* __restrict__ dst, int o, f32x4_t a)
{
    ushort4 s;
    s.x = f16b(fmaxf(a[0], 0.f));
    s.y = f16b(fmaxf(a[1], 0.f));
    s.z = f16b(fmaxf(a[2], 0.f));
    s.w = f16b(fmaxf(a[3], 0.f));
    *(ushort4*)&dst[o] = s;
}

__global__ __launch_bounds__(512, 6)
void made_flow_r19(const float* __restrict__ inputs,
                   const float* __restrict__ W1,
                   const float* __restrict__ W2,
                   const float* __restrict__ Wout,
                   const int* __restrict__ idx,
                   const int* __restrict__ valid,
                   const int* __restrict__ M1,
                   const int* __restrict__ M2,
                   const int* __restrict__ Mout,
                   float* __restrict__ out)
{
    __shared__ __align__(16) u16 h1s[TROWS * SHP];      // 8704 B (staging scratch A)
    __shared__ __align__(16) u16 h2s[TROWS * SHP];      // 8704 B (staging scratch B)
    __shared__ __align__(16) u16 wout_lds[OO * SSC];    // 17408 B (Wout^T resident)
    __shared__ __align__(16) u16 xgh[2][TROWS * SXG];   // 5120 B
    __shared__ __align__(16) float red2[2][TROWS][4];   // 1024 B
    __shared__ int   idx_s[RR];
    __shared__ float v_s[RR];
    // total ~41.3 KB -> 3 blocks/CU (reg-permitting)

    u16* const scr  = h1s;
    u16* const scr2 = h2s;

    const int tid  = threadIdx.x;
    const int r    = blockIdx.x / BLOCKS_PER_R;
    const int rb   = blockIdx.x % BLOCKS_PER_R;
    // tile range: first 16 blocks take 11 tiles, last 8 take 10 (total 256)
    const int ts   = (rb < 16) ? 11 * rb : 176 + 10 * (rb - 16);
    const int nt   = (rb < 16) ? 11 : 10;

    const int lane = tid & 63;
    const int wave = tid >> 6;     // 0..7
    const int q    = lane >> 4;
    const int l16  = lane & 15;
    const int wm3  = wave & 3;     // P3: o-col group 16*wm3
    const int ni3  = wave >> 2;    // P3: batch-row half

    if (tid < RR) {
        idx_s[tid] = idx[r * RR + tid];
        v_s[tid]   = valid[r * RR + tid] ? 1.f : 0.f;
    }

    // ---- stage weights: a1,a2 -> regs; Wout^T -> resident LDS ----
    f16x8_t a1;        // W1^T: wave cols 16w+l16, k=q*8..
    f16x8_t a2[4];     // W2^T: [ks], wave cols 16w+l16
    {
        const float* W1r = W1 + r * RR * HH;   const int* M1r = M1 + r * RR * HH;
        const float* W2r = W2 + r * HH * HH;   const int* M2r = M2 + r * HH * HH;
        const float* Wor = Wout + r * HH * OO; const int* Mor = Mout + r * HH * OO;
        const int c = wave >> 1, h = wave & 1;
        for (int i = 0; i < 2; ++i) {
            __syncthreads();
            if (tid < 256) stage_block16(W2r, M2r, HH, 32 * (2 * i),     HH, scr,  tid);
            else           stage_block16(W2r, M2r, HH, 32 * (2 * i + 1), HH, scr2, tid - 256);
            __syncthreads();
            if (c == 2 * i) {
#pragma unroll
                for (int ks = 0; ks < 4; ++ks)
                    a2[ks] = *(const f16x8_t*)&scr[(16 * h + l16) * SSC + ks * 32 + q * 8];
            } else if (c == 2 * i + 1) {
#pragma unroll
                for (int ks = 0; ks < 4; ++ks)
                    a2[ks] = *(const f16x8_t*)&scr2[(16 * h + l16) * SSC + ks * 32 + q * 8];
            }
        }
        for (int i = 0; i < 2; ++i) {
            __syncthreads();
            if (tid < 256) stage_block16(W1r, M1r, HH, 32 * (2 * i),     RR, scr,  tid);
            else           stage_block16(W1r, M1r, HH, 32 * (2 * i + 1), RR, scr2, tid - 256);
            __syncthreads();
            if (c == 2 * i)          a1 = *(const f16x8_t*)&scr [(16 * h + l16) * SSC + q * 8];
            else if (c == 2 * i + 1) a1 = *(const f16x8_t*)&scr2[(16 * h + l16) * SSC + q * 8];
        }
        // Wout^T -> wout_lds (read-only for the rest of the kernel)
        if (tid < 256) stage_block16(Wor, Mor, OO, 0,  HH, wout_lds,            tid);
        else           stage_block16(Wor, Mor, OO, 32, HH, wout_lds + 32 * SSC, tid - 256);
    }
    __syncthreads();   // staging done before xg/h1 writes; idx_s/v_s visible

    const f32x4_t zero4 = {0.f, 0.f, 0.f, 0.f};
    const int grow = tid >> 4;     // 0..31 batch row (gather role)
    const int gg   = tid & 15;     // col pair: 2*gg, 2*gg+1
    const int   ci0 = idx_s[2 * gg], ci1 = idx_s[2 * gg + 1];
    const float cv0 = v_s[2 * gg],   cv1 = v_s[2 * gg + 1];
    const int j0  = 8 * wm3 + 2 * q;                    // epilogue cols
    const float vj0 = v_s[j0], vj1 = v_s[j0 + 1];
    const int gbase = (ts * TROWS + grow) * DD;

    // ---- prologue: gather(0) -> xgh[0]; issue gather(1) into regs ----
    float gx0, gx1;
    {
        float a0  = inputs[gbase + ci0] * cv0;
        float a1v = inputs[gbase + ci1] * cv1;
        *(u32*)&xgh[0][grow * SXG + 2 * gg] = (u32)f16b(a0) | ((u32)f16b(a1v) << 16);
        gx0 = inputs[gbase + TROWS * DD + ci0] * cv0;
        gx1 = inputs[gbase + TROWS * DD + ci1] * cv1;
    }
    __syncthreads();

    // ---- prologue: P1(0) -> h1s ----
    {
#pragma unroll
        for (int ni = 0; ni < 2; ++ni) {
            f16x8_t b = *(const f16x8_t*)&xgh[0][(16 * ni + l16) * SXG + q * 8];
            f32x4_t a = mfma16h(a1, b, zero4);
            relu_store16(h1s, (16 * ni + l16) * SHP + 16 * wave + 4 * q, a);
        }
    }

    for (int t = 0; t < nt; ++t) {
        __syncthreads();   // head barrier

        const bool dg = (t + 1 < nt);

        // ========== interval A: gather-store(t+1) + P2(t) + out-store(t-2) ========
        if (dg) {
            *(u32*)&xgh[(t + 1) & 1][grow * SXG + 2 * gg] =
                (u32)f16b(gx0) | ((u32)f16b(gx1) << 16);
        }
        {
            // P2(t): h2^T = W2^T @ h1^T (wave owns 16 of M=128 cols, both ni, K=128)
            f32x4_t acc[2] = {zero4, zero4};
#pragma unroll
            for (int ks = 0; ks < 4; ++ks) {
#pragma unroll
                for (int ni = 0; ni < 2; ++ni) {
                    f16x8_t b = *(const f16x8_t*)&h1s[(16 * ni + l16) * SHP + ks * 32 + q * 8];
                    acc[ni] = mfma16h(a2[ks], b, acc[ni]);
                }
            }
#pragma unroll
            for (int ni = 0; ni < 2; ++ni)
                relu_store16(h2s, (16 * ni + l16) * SHP + 16 * wave + 4 * q, acc[ni]);
        }
        if (t >= 2 && tid < TROWS) {
            float4 rv = *(const float4*)&red2[t & 1][tid][0];
            out[((ts + (t - 2)) * TROWS + tid) * RR + r] =
                rv.x + rv.y + rv.z + rv.w;
        }
        __syncthreads();   // mid barrier

        // ========== interval B: gather-issue(t+2) + P3(t) + P1(t+1) + epilogue(t) ==
        if (t + 2 < nt) {
            const int base = gbase + (t + 2) * (TROWS * DD);
            gx0 = inputs[base + ci0] * cv0;
            gx1 = inputs[base + ci1] * cv1;
        }

        // P3(t): out^T = Wout^T @ h2^T; wave (wm3,ni3): o=16*wm3+4q+i, row=16*ni3+l16
        // A-frags from resident wout_lds (4 bank-balanced ds_read_b128)
        f32x4_t acc3 = zero4;
#pragma unroll
        for (int ks = 0; ks < 4; ++ks) {
            f16x8_t ao = *(const f16x8_t*)&wout_lds[(16 * wm3 + l16) * SSC + ks * 32 + q * 8];
            f16x8_t b  = *(const f16x8_t*)&h2s[(16 * ni3 + l16) * SHP + ks * 32 + q * 8];
            acc3 = mfma16h(ao, b, acc3);
        }

        if (dg) {   // P1(t+1): h1^T = W1^T @ xg^T
#pragma unroll
            for (int ni = 0; ni < 2; ++ni) {
                f16x8_t b = *(const f16x8_t*)&xgh[(t + 1) & 1][(16 * ni + l16) * SXG + q * 8];
                f32x4_t a = mfma16h(a1, b, zero4);
                relu_store16(h1s, (16 * ni + l16) * SHP + 16 * wave + 4 * q, a);
            }
        }

        {   // epilogue(t): acc3[i]: i even=shift(j), i odd=log_s(j), j=8*wm3+2q+(i>>1)
            const int row = 16 * ni3 + l16;
            u32 xw = *(const u32*)&xgh[t & 1][row * SXG + j0];
            union { u32 u; _Float16 h[2]; } xc; xc.u = xw;
            const float xv0 = (float)xc.h[0], xv1 = (float)xc.h[1];
            const float u0 = (xv0 - acc3[0]) * __expf(-acc3[1]);
            const float u1 = (xv1 - acc3[2]) * __expf(-acc3[3]);
            float p = (-0.5f * u0 * u0 - 0.91893853320467266954f - acc3[1]) * vj0
                    + (-0.5f * u1 * u1 - 0.91893853320467266954f - acc3[3]) * vj1;
            p += __shfl_xor(p, 16, 64);
            p += __shfl_xor(p, 32, 64);
            if (q == 0) red2[t & 1][row][wm3] = p;
        }
    }

    // ---- tail: store tiles nt-2 and nt-1 ----
    __syncthreads();
    if (tid < 2 * TROWS) {
        const int tt  = nt - 2 + (tid >> 5);
        const int row = tid & 31;
        float4 rv = *(const float4*)&red2[tt & 1][row][0];
        out[((ts + tt) * TROWS + row) * RR + r] =
            rv.x + rv.y + rv.z + rv.w;
    }
}

extern "C" void kernel_launch(void* const* d_in, const int* in_sizes, int n_in,
                              void* d_out, int out_size, void* d_ws, size_t ws_size,
                              hipStream_t stream)
{
    const float* inputs = (const float*)d_in[0];
    const float* W1     = (const float*)d_in[1];
    const float* W2     = (const float*)d_in[2];
    const float* Wout   = (const float*)d_in[3];
    const int*   idx    = (const int*)d_in[4];
    const int*   valid  = (const int*)d_in[5];
    const int*   M1     = (const int*)d_in[6];
    const int*   M2     = (const int*)d_in[7];
    const int*   Mout   = (const int*)d_in[8];
    float*       out    = (float*)d_out;

    hipLaunchKernelGGL(made_flow_r19, dim3(RR * BLOCKS_PER_R), dim3(512), 0, stream,
                       inputs, W1, W2, Wout, idx, valid, M1, M2, Mout, out);
}